// Round 5
// baseline (220.505 us; speedup 1.0000x reference)
//
#include <hip/hip_runtime.h>

// out = sign * FWHT(x), x: 16384 x 2048 fp32; scale 2^-5.5 fused; sign = -1
// for n >= 1536 (n10&n9).
//
// One wave per row, 32 elements/lane: v[k][e], n = (k2 k1 k0 | l5..l0 | e1 e0).
// Butterfly (all stages commute):
//   per k: bits 0,1 (reg); bit2 lane^1 (DPP); bit3 lane^2 (DPP);
//          bit4 lane^4 (DPP mirror pair); bit5 lane^8 (DPP mirror pair)
//   bits 8,9,10: register butterflies across k
//   bit 7: v_permlane32_swap + reg butterfly
//   bit 6: v_permlane16_swap + reg butterfly; scale fused into store
// No LDS-pipe ops.
//
// Flavor (settled r0-r3): NT loads + NT stores. Regular loads = 80 us kernel
// (harness fills flush L3 -> mixed hit/miss read path 25% slower than pure
// streaming). Store flavor neutral.
//
// Round 5 experiment: burst homogeneity. 4 rows/wave straight-line:
//   32-load burst (32KB in flight, vmcnt<=32) -> [compute r0, r1] ->
//   16-store burst -> [compute r2, r3] -> 16-store burst.
// Theory: kernel sits at 3.95 TB/s vs 6.29 TB/s copy ceiling because waves
// present fine-grained alternating 8KB R/W bursts to HBM; wider homogeneous
// bursts per wave reduce channel R/W turnaround. sched_barrier(0) pins the
// load burst ahead of compute. ~160 VGPR -> 3 waves/SIMD (MLP still ample).
// Spill watch: r2 showed spills (VGPR capped) cost +24 us; if VGPR table
// shows spills this experiment is void, not a mechanism refutation.
//
// Final layout: n = k2*1024 + k1*512 + l5*256 + l4*128 + k0*64 + (l&15)*4 + e

#define NN 2048

typedef float f4 __attribute__((ext_vector_type(4)));
typedef unsigned int v2u __attribute__((ext_vector_type(2)));

template <int CTRL>
__device__ __forceinline__ float dppf(float x) {
    return __int_as_float(__builtin_amdgcn_mov_dpp(__float_as_int(x), CTRL, 0xF, 0xF, true));
}

// lane^4 / lane^8 partner via two DPP movs (pure VALU, no LDS pipe).
// 0x141 = ROW_HALF_MIRROR (lane^7 in 8), 0x140 = ROW_MIRROR (lane^15 in 16),
// 0x1B = quad_perm{3,2,1,0} (lane^3). 7^3 = 4, 15^7 = 8.
__device__ __forceinline__ float xor4f(float x) { return dppf<0x1B>(dppf<0x141>(x)); }
__device__ __forceinline__ float xor8f(float x) { return dppf<0x141>(dppf<0x140>(x)); }

#if __has_builtin(__builtin_amdgcn_permlane32_swap)
#define HAVE_PLSWAP 1
__device__ __forceinline__ void pl32_swap(float& a, float& b) {
    v2u r = __builtin_amdgcn_permlane32_swap(__float_as_uint(a), __float_as_uint(b), false, false);
    a = __uint_as_float(r[0]);
    b = __uint_as_float(r[1]);
}
__device__ __forceinline__ void pl16_swap(float& a, float& b) {
    v2u r = __builtin_amdgcn_permlane16_swap(__float_as_uint(a), __float_as_uint(b), false, false);
    a = __uint_as_float(r[0]);
    b = __uint_as_float(r[1]);
}
#else
#define HAVE_PLSWAP 0
#endif

__device__ __forceinline__ void load_row(float (&v)[8][4], const float* __restrict__ xr,
                                         int lane) {
#pragma unroll
    for (int k = 0; k < 8; ++k) {
        const f4 t = __builtin_nontemporal_load(
            reinterpret_cast<const f4*>(xr + 256 * k + 4 * lane));
        v[k][0] = t[0]; v[k][1] = t[1]; v[k][2] = t[2]; v[k][3] = t[3];
    }
}

__device__ __forceinline__ void fwht_compute(float (&v)[8][4],
                                             float s2, float s3, float s4, float s5,
                                             int lane) {
    // ---- per-k lane-local stages: bits 0,1 then 2,3,4,5 ----
#pragma unroll
    for (int k = 0; k < 8; ++k) {
        {
            float a0 = v[k][0], a1 = v[k][1], a2 = v[k][2], a3 = v[k][3];
            float b0 = a0 + a1, b1 = a0 - a1, b2 = a2 + a3, b3 = a2 - a3;
            v[k][0] = b0 + b2; v[k][1] = b1 + b3;
            v[k][2] = b0 - b2; v[k][3] = b1 - b3;
        }
#pragma unroll
        for (int e = 0; e < 4; ++e) {
            const float w = dppf<0xB1>(v[k][e]);  // lane^1
            v[k][e] = fmaf(s2, v[k][e], w);
        }
#pragma unroll
        for (int e = 0; e < 4; ++e) {
            const float w = dppf<0x4E>(v[k][e]);  // lane^2
            v[k][e] = fmaf(s3, v[k][e], w);
        }
#pragma unroll
        for (int e = 0; e < 4; ++e) {
            const float w = xor4f(v[k][e]);       // lane^4
            v[k][e] = fmaf(s4, v[k][e], w);
        }
#pragma unroll
        for (int e = 0; e < 4; ++e) {
            const float w = xor8f(v[k][e]);       // lane^8
            v[k][e] = fmaf(s5, v[k][e], w);
        }
    }

    // ---- bits 8,9,10 (across k) ----
#pragma unroll
    for (int e = 0; e < 4; ++e) {
#pragma unroll
        for (int k = 0; k < 8; k += 2) {
            float a = v[k][e], b = v[k + 1][e];
            v[k][e] = a + b; v[k + 1][e] = a - b;
        }
#pragma unroll
        for (int k = 0; k < 8; k += 4) {
            float a0 = v[k][e], a1 = v[k + 1][e], b0 = v[k + 2][e], b1 = v[k + 3][e];
            v[k][e] = a0 + b0; v[k + 1][e] = a1 + b1;
            v[k + 2][e] = a0 - b0; v[k + 3][e] = a1 - b1;
        }
#pragma unroll
        for (int k = 0; k < 4; ++k) {
            float a = v[k][e], b = v[k + 4][e];
            v[k][e] = a + b; v[k + 4][e] = a - b;
        }
    }

#if HAVE_PLSWAP
    // ---- bit 7: permlane32_swap + reg butterfly ----
#pragma unroll
    for (int j = 0; j < 4; ++j)
#pragma unroll
        for (int e = 0; e < 4; ++e) {
            pl32_swap(v[2 * j][e], v[2 * j + 1][e]);
            float a = v[2 * j][e], b = v[2 * j + 1][e];
            v[2 * j][e] = a + b; v[2 * j + 1][e] = a - b;
        }
    // ---- bit 6: permlane16_swap + reg butterfly (scale deferred to store) ----
#pragma unroll
    for (int j = 0; j < 4; ++j)
#pragma unroll
        for (int e = 0; e < 4; ++e) {
            pl16_swap(v[2 * j][e], v[2 * j + 1][e]);
            float a = v[2 * j][e], b = v[2 * j + 1][e];
            v[2 * j][e] = a + b; v[2 * j + 1][e] = a - b;
        }
#else
    // Fallback: bits 6,7 via shfl_xor (lane bits 4,5).
#pragma unroll
    for (int s6 = 4; s6 < 6; ++s6) {
        const int m = 1 << s6;
        const float s = (lane & m) ? -1.0f : 1.0f;
#pragma unroll
        for (int k = 0; k < 8; ++k)
#pragma unroll
            for (int e = 0; e < 4; ++e) {
                const float w = __shfl_xor(v[k][e], m, 64);
                v[k][e] = fmaf(s, v[k][e], w);
            }
    }
#endif
}

__device__ __forceinline__ void store_row(float (&v)[8][4], float* __restrict__ outr,
                                          int lane, int lanebase) {
    const float M = 0.022097086912079608f;  // 2^-5.5
#if HAVE_PLSWAP
    // n = k2*1024 + k1*512 + l5*256 + l4*128 + k0*64 + (l&15)*4 + e
#pragma unroll
    for (int k = 0; k < 8; ++k) {
        const float mk = (k >= 6) ? -M : M;  // sign = n10&n9 = k2&k1
        const int base = ((k >> 2) & 1) * 1024 + ((k >> 1) & 1) * 512 + (k & 1) * 64;
        f4 t;
        t[0] = v[k][0] * mk; t[1] = v[k][1] * mk;
        t[2] = v[k][2] * mk; t[3] = v[k][3] * mk;
        __builtin_nontemporal_store(t, reinterpret_cast<f4*>(outr + base + lanebase));
    }
#else
#pragma unroll
    for (int k = 0; k < 8; ++k) {
        const float mk = (k >= 6) ? -M : M;
        f4 t;
        t[0] = v[k][0] * mk; t[1] = v[k][1] * mk;
        t[2] = v[k][2] * mk; t[3] = v[k][3] * mk;
        __builtin_nontemporal_store(t, reinterpret_cast<f4*>(outr + 256 * k + 4 * lane));
    }
#endif
}

__global__ __launch_bounds__(256)
void fwht_sign_kernel(const float* __restrict__ x, float* __restrict__ out) {
    const int lane = threadIdx.x & 63;
    const int wid  = threadIdx.x >> 6;
    const long long wave = (long long)blockIdx.x * 4 + wid;
    const long long S    = (long long)gridDim.x * 4;   // 4096 waves total

    const float s2 = (lane & 1) ? -1.0f : 1.0f;
    const float s3 = (lane & 2) ? -1.0f : 1.0f;
    const float s4 = (lane & 4) ? -1.0f : 1.0f;
    const float s5 = (lane & 8) ? -1.0f : 1.0f;
    const int lanebase = ((lane >> 5) & 1) * 256 + ((lane >> 4) & 1) * 128 + (lane & 15) * 4;

    const long long r0 = wave, r1 = wave + S, r2 = wave + 2 * S, r3 = wave + 3 * S;

    float A[8][4], B[8][4], C[8][4], D[8][4];

    // ---- 32-load burst: 4 rows, 32 KB in flight per wave ----
    load_row(A, x + r0 * NN, lane);
    load_row(B, x + r1 * NN, lane);
    load_row(C, x + r2 * NN, lane);
    load_row(D, x + r3 * NN, lane);
    __builtin_amdgcn_sched_barrier(0);  // pin the load burst ahead of compute

    // ---- compute pair 0, then 16-store burst ----
    fwht_compute(A, s2, s3, s4, s5, lane);
    fwht_compute(B, s2, s3, s4, s5, lane);
    store_row(A, out + r0 * NN, lane, lanebase);
    store_row(B, out + r1 * NN, lane, lanebase);

    // ---- compute pair 1, then 16-store burst ----
    fwht_compute(C, s2, s3, s4, s5, lane);
    fwht_compute(D, s2, s3, s4, s5, lane);
    store_row(C, out + r2 * NN, lane, lanebase);
    store_row(D, out + r3 * NN, lane, lanebase);
}

extern "C" void kernel_launch(void* const* d_in, const int* in_sizes, int n_in,
                              void* d_out, int out_size, void* d_ws, size_t ws_size,
                              hipStream_t stream) {
    const float* x = (const float*)d_in[0];
    float* out = (float*)d_out;
    const int rows = in_sizes[0] / NN;          // 16384
    const int blocks = rows / 16;               // 4 waves/block x 4 rows/wave
    fwht_sign_kernel<<<dim3(blocks), dim3(256), 0, stream>>>(x, out);
}